// Round 3
// baseline (331.788 us; speedup 1.0000x reference)
//
#include <hip/hip_runtime.h>
#include <math.h>

#define NN 2048
#define FF 128
#define UU 128
#define FE 16
#define DEG 64

// ---------------- Kernel 1: hl/hr GEMM + al/ar reduction + wef ----------------
// 256 blocks x 256 threads, 8 nodes per block. hl never touches memory:
// al[n] = sum_u lrelu(hl[n][u]) * Wa[u] is reduced in-block.
__global__ __launch_bounds__(256) void prep(
    const float* __restrict__ ns, const float* __restrict__ Wl,
    const float* __restrict__ Wr, const float* __restrict__ Wa,
    const float* __restrict__ We,
    float* __restrict__ hr, float* __restrict__ al, float* __restrict__ ar,
    float* __restrict__ wef)
{
    __shared__ float sns[8][FF];
    __shared__ float swl[4][4], swr[4][4];
    const int nb  = blockIdx.x * 8;
    const int tid = threadIdx.x;
    {
        const int idx = tid * 4;
        ((float4*)&sns[idx >> 7][idx & 127])[0] =
            ((const float4*)(ns + (size_t)nb * FF))[tid];
    }
    __syncthreads();

    const int u  = tid & 127;
    const int ng = tid >> 7;           // node group: nodes ng*4 .. ng*4+3
    float accl[4] = {0.f, 0.f, 0.f, 0.f};
    float accr[4] = {0.f, 0.f, 0.f, 0.f};
#pragma unroll 4
    for (int k = 0; k < FF; ++k) {
        const float wl = Wl[k * UU + u];
        const float wr = Wr[k * UU + u];
#pragma unroll
        for (int j = 0; j < 4; ++j) {
            const float a = sns[ng * 4 + j][k];   // wave-uniform broadcast
            accl[j] += a * wl;
            accr[j] += a * wr;
        }
    }

    const float wa_l = Wa[u];
    const float wa_r = Wa[UU + u];
    float xl[4], xr[4];
#pragma unroll
    for (int j = 0; j < 4; ++j) {
        hr[(size_t)(nb + ng * 4 + j) * UU + u] = accr[j];
        const float l = accl[j];
        const float r = accr[j];
        xl[j] = (l > 0.f ? l : 0.2f * l) * wa_l;
        xr[j] = (r > 0.f ? r : 0.2f * r) * wa_r;
    }
#pragma unroll
    for (int o = 32; o > 0; o >>= 1) {
#pragma unroll
        for (int j = 0; j < 4; ++j) {
            xl[j] += __shfl_xor(xl[j], o);
            xr[j] += __shfl_xor(xr[j], o);
        }
    }
    const int wave = tid >> 6;
    if ((tid & 63) == 0) {
#pragma unroll
        for (int j = 0; j < 4; ++j) { swl[wave][j] = xl[j]; swr[wave][j] = xr[j]; }
    }
    __syncthreads();
    if (tid < 8) {
        const int g = tid >> 2, j = tid & 3;
        al[nb + tid] = swl[2 * g][j] + swl[2 * g + 1][j];
        ar[nb + tid] = swr[2 * g][j] + swr[2 * g + 1][j];
    }
    if (blockIdx.x == 0 && tid < FE) {
        float s = 0.f;
#pragma unroll
        for (int j = 0; j < FE; ++j) s += We[tid * FE + j] * Wa[2 * UU + j];
        wef[tid] = s;
    }
}

// ---------------- Kernel 2: edge scores + softmax + output ----------------
// Two src nodes per 256-thread block (src == segment index, DEG contiguous
// edges each). Waves 0/1 score nodes 2b / 2b+1; all 4 waves then produce the
// two 128-unit output rows.
__global__ __launch_bounds__(256) void edge_out(
    const float* __restrict__ hr, const float* __restrict__ al,
    const float* __restrict__ ar, const int* __restrict__ edges,
    const float* __restrict__ ef, const float* __restrict__ wef,
    float* __restrict__ out)
{
    const int b   = blockIdx.x * 2;   // first node of pair
    const int tid = threadIdx.x;
    __shared__ float sattn[2][DEG];
    __shared__ int   sdst[2][DEG];

    if (tid < 2 * DEG) {
        const int p    = tid >> 6;        // 0 or 1: which node (== wave id)
        const int e    = tid & 63;
        const int node = b + p;
        const int dst  = ((const int2*)edges)[node * DEG + e].y;  // coalesced 8B
        const float4* efp = (const float4*)(ef + ((size_t)node * NN + dst) * FE);
        float s = al[node] + ar[dst];     // al[node] wave-uniform -> scalar load
#pragma unroll
        for (int q = 0; q < 4; ++q) {
            const float4 v = efp[q];
            s += v.x * wef[4 * q + 0] + v.y * wef[4 * q + 1]
               + v.z * wef[4 * q + 2] + v.w * wef[4 * q + 3];
        }
        s = fminf(fmaxf(s, -2.f), 2.f);
        const float sc = expf(s);
        float tot = sc;
#pragma unroll
        for (int o = 32; o > 0; o >>= 1) tot += __shfl_xor(tot, o);
        sattn[p][e] = sc / tot;
        sdst[p][e]  = dst;
    }
    __syncthreads();

    const int p = tid >> 7;           // 0 or 1: which node's output row
    const int u = tid & 127;          // output unit
    float acc = 0.f;
#pragma unroll 8
    for (int e = 0; e < DEG; ++e) {
        acc += sattn[p][e] * hr[(size_t)sdst[p][e] * UU + u];
    }
    out[(size_t)(b + p) * UU + u] = acc;
}

extern "C" void kernel_launch(void* const* d_in, const int* in_sizes, int n_in,
                              void* d_out, int out_size, void* d_ws, size_t ws_size,
                              hipStream_t stream) {
    const float* ns  = (const float*)d_in[0];
    const int*   edg = (const int*)d_in[1];
    const float* ef  = (const float*)d_in[2];
    const float* Wl  = (const float*)d_in[3];
    const float* Wr  = (const float*)d_in[4];
    const float* Wa  = (const float*)d_in[5];
    const float* We  = (const float*)d_in[6];
    float* out = (float*)d_out;

    float* hr  = (float*)d_ws;              // 1 MB
    float* al  = hr + (size_t)NN * UU;      // 8 KB
    float* ar  = al + NN;                   // 8 KB
    float* wef = ar + NN;                   // 64 B

    prep<<<NN / 8, 256, 0, stream>>>(ns, Wl, Wr, Wa, We, hr, al, ar, wef);
    edge_out<<<NN / 2, 256, 0, stream>>>(hr, al, ar, edg, ef, wef, out);
}